// Round 9
// baseline (149.597 us; speedup 1.0000x reference)
//
#include <hip/hip_runtime.h>

// PointPillars scatter: canvas[b, c, y, x] = feat[n, c] where coords[n] = (b, _, y, x)
// R9: DIAGNOSTIC A/B. R4 kernel kept verbatim (known 89.1us total); prepend
// pps_store_zero = R4's exact K3 store pattern with loads removed (writes
// zeros, nt). Real K3 overwrites -> output correct. Total = 89.1 + T(K3z):
//   ~140us -> store pattern fine, reads are the bottleneck.
//   ~165us -> strided-plane store pattern is the wall even load-free.

#define NXD 400
#define NYD 400
#define CCH 64
#define NXY (NXD * NYD)   // 160000 cells/sample, divisible by 4

typedef float fvec4 __attribute__((ext_vector_type(4)));
typedef int   ivec4 __attribute__((ext_vector_type(4)));

__global__ void pps_init_map(ivec4* __restrict__ map4, int total4) {
    int i = blockIdx.x * blockDim.x + threadIdx.x;
    int stride = gridDim.x * blockDim.x;
    ivec4 neg1 = {-1, -1, -1, -1};
    for (; i < total4; i += stride)
        __builtin_nontemporal_store(neg1, map4 + i);
}

__global__ void pps_build_map(const int* __restrict__ coords, int* __restrict__ map, int n) {
    int i = blockIdx.x * blockDim.x + threadIdx.x;
    if (i >= n) return;
    ivec4 c4 = *(const ivec4*)(coords + i * 4);   // (b, _, y, x)
    map[c4.x * NXY + c4.z * NXD + c4.w] = i;
}

// ---- DIAGNOSTIC: R4's store pattern, zero loads ----
__global__ __launch_bounds__(1024) void pps_store_zero(float* __restrict__ out,
                                                       int total_pos) {
    int t = blockIdx.x * blockDim.x + threadIdx.x;
    int pos4 = t * 4;
    if (pos4 >= total_pos) return;

    int b = pos4 / NXY;
    int s = pos4 - b * NXY;
    float* outp = out + (size_t)b * CCH * NXY + s;

    const fvec4 zero = {0.f, 0.f, 0.f, 0.f};
    #pragma unroll 4
    for (int g = 0; g < CCH / 4; ++g) {
        __builtin_nontemporal_store(zero, (fvec4*)(outp + (size_t)(4 * g + 0) * NXY));
        __builtin_nontemporal_store(zero, (fvec4*)(outp + (size_t)(4 * g + 1) * NXY));
        __builtin_nontemporal_store(zero, (fvec4*)(outp + (size_t)(4 * g + 2) * NXY));
        __builtin_nontemporal_store(zero, (fvec4*)(outp + (size_t)(4 * g + 3) * NXY));
    }
}

// ---- R4's K3, verbatim ----
__global__ __launch_bounds__(1024) void pps_gather_out(const float* __restrict__ feat,
                                                       const int* __restrict__ map,
                                                       float* __restrict__ out,
                                                       int total_pos) {
    int t = blockIdx.x * blockDim.x + threadIdx.x;
    int pos4 = t * 4;
    if (pos4 >= total_pos) return;

    ivec4 m = __builtin_nontemporal_load((const ivec4*)(map + pos4)); // single-use

    int b = pos4 / NXY;                  // 4 cells never straddle a sample (NXY%4==0)
    int s = pos4 - b * NXY;
    float* outp = out + (size_t)b * CCH * NXY + s;

    const bool o0 = m.x >= 0, o1 = m.y >= 0, o2 = m.z >= 0, o3 = m.w >= 0;
    const fvec4* f0 = (const fvec4*)(feat + (size_t)(o0 ? m.x : 0) * CCH);
    const fvec4* f1 = (const fvec4*)(feat + (size_t)(o1 ? m.y : 0) * CCH);
    const fvec4* f2 = (const fvec4*)(feat + (size_t)(o2 ? m.z : 0) * CCH);
    const fvec4* f3 = (const fvec4*)(feat + (size_t)(o3 ? m.w : 0) * CCH);

    const fvec4 zero = {0.f, 0.f, 0.f, 0.f};

    #pragma unroll 4
    for (int g = 0; g < CCH / 4; ++g) {
        fvec4 a0 = f0[g];
        fvec4 a1 = f1[g];
        fvec4 a2 = f2[g];
        fvec4 a3 = f3[g];
        if (!o0) a0 = zero;
        if (!o1) a1 = zero;
        if (!o2) a2 = zero;
        if (!o3) a3 = zero;
        fvec4 v0 = {a0.x, a1.x, a2.x, a3.x};
        fvec4 v1 = {a0.y, a1.y, a2.y, a3.y};
        fvec4 v2 = {a0.z, a1.z, a2.z, a3.z};
        fvec4 v3 = {a0.w, a1.w, a2.w, a3.w};
        __builtin_nontemporal_store(v0, (fvec4*)(outp + (size_t)(4 * g + 0) * NXY));
        __builtin_nontemporal_store(v1, (fvec4*)(outp + (size_t)(4 * g + 1) * NXY));
        __builtin_nontemporal_store(v2, (fvec4*)(outp + (size_t)(4 * g + 2) * NXY));
        __builtin_nontemporal_store(v3, (fvec4*)(outp + (size_t)(4 * g + 3) * NXY));
    }
}

extern "C" void kernel_launch(void* const* d_in, const int* in_sizes, int n_in,
                              void* d_out, int out_size, void* d_ws, size_t ws_size,
                              hipStream_t stream) {
    const float* feat  = (const float*)d_in[0];   // [N, 64] fp32
    const int* coords  = (const int*)d_in[1];     // [N, 4] int32 (b, _, y, x)
    float* out         = (float*)d_out;           // [B, 64, NY, NX] fp32

    const int n_pillars = in_sizes[1] / 4;
    const int batch     = out_size / (CCH * NXY);
    const int total_pos = batch * NXY;            // 1.28M cells

    int* map = (int*)d_ws;                        // batch*NXY*4 = 5.12 MB

    int threads = total_pos / 4;                  // 320000
    int grid1024 = (threads + 1023) / 1024;       // 313

    // DIAGNOSTIC: pure-store calibration of R4's pattern (overwritten by K3)
    pps_store_zero<<<grid1024, 1024, 0, stream>>>(out, total_pos);

    // K1: reset map every call (d_ws not re-poisoned between replays)
    pps_init_map<<<1024, 256, 0, stream>>>((ivec4*)map, total_pos / 4);

    // K2: scatter pillar indices into the map
    pps_build_map<<<(n_pillars + 255) / 256, 256, 0, stream>>>(coords, map, n_pillars);

    // K3: R4's gather pass, verbatim
    pps_gather_out<<<grid1024, 1024, 0, stream>>>(feat, map, out, total_pos);
}

// Round 10
// 73.625 us; speedup vs baseline: 2.0319x; 2.0319x over previous
//
#include <hip/hip_runtime.h>

// PointPillars scatter: canvas[b, c, y, x] = feat[n, c] where coords[n] = (b, _, y, x)
// R10: R4 store structure + balanced 256-thread grid + explicit depth-1
// software pipeline (prefetch channel-quad g+1's four fvec4 gathers before
// issuing g's stores, double-buffered in registers).
//   K1: map[:] = -1
//   K2: map[b*NY*NX + y*NX + x] = n          (collision-free per problem spec)
//   K3: thread owns 4 consecutive x-cells; 16 channel-quad iterations,
//       4x4 register transpose, nt fvec4 stores. Empty slots clamp to row 0
//       (broadcast line) + cndmask-zero.

#define NXD 400
#define NYD 400
#define CCH 64
#define NXY (NXD * NYD)   // 160000 cells/sample, divisible by 4

typedef float fvec4 __attribute__((ext_vector_type(4)));
typedef int   ivec4 __attribute__((ext_vector_type(4)));

__global__ void pps_init_map(ivec4* __restrict__ map4, int total4) {
    int i = blockIdx.x * blockDim.x + threadIdx.x;
    int stride = gridDim.x * blockDim.x;
    ivec4 neg1 = {-1, -1, -1, -1};
    for (; i < total4; i += stride)
        __builtin_nontemporal_store(neg1, map4 + i);
}

__global__ void pps_build_map(const int* __restrict__ coords, int* __restrict__ map, int n) {
    int i = blockIdx.x * blockDim.x + threadIdx.x;
    if (i >= n) return;
    ivec4 c4 = *(const ivec4*)(coords + i * 4);   // (b, _, y, x)
    map[c4.x * NXY + c4.z * NXD + c4.w] = i;
}

__global__ __launch_bounds__(256) void pps_gather_out(const float* __restrict__ feat,
                                                      const int* __restrict__ map,
                                                      float* __restrict__ out,
                                                      int total_pos) {
    int t = blockIdx.x * blockDim.x + threadIdx.x;
    int pos4 = t * 4;
    if (pos4 >= total_pos) return;

    ivec4 m = __builtin_nontemporal_load((const ivec4*)(map + pos4)); // single-use

    int b = pos4 / NXY;                  // 4 cells never straddle a sample (NXY%4==0)
    int s = pos4 - b * NXY;
    float* outp = out + (size_t)b * CCH * NXY + s;

    const bool o0 = m.x >= 0, o1 = m.y >= 0, o2 = m.z >= 0, o3 = m.w >= 0;
    // Clamp empty slots to row 0: valid memory, broadcast cache line.
    const fvec4* f0 = (const fvec4*)(feat + (size_t)(o0 ? m.x : 0) * CCH);
    const fvec4* f1 = (const fvec4*)(feat + (size_t)(o1 ? m.y : 0) * CCH);
    const fvec4* f2 = (const fvec4*)(feat + (size_t)(o2 ? m.z : 0) * CCH);
    const fvec4* f3 = (const fvec4*)(feat + (size_t)(o3 ? m.w : 0) * CCH);

    const fvec4 zero = {0.f, 0.f, 0.f, 0.f};

    // ---- depth-1 software pipeline over 16 channel-quads ----
    fvec4 A0 = f0[0], A1 = f1[0], A2 = f2[0], A3 = f3[0];

    #pragma unroll
    for (int g = 0; g < CCH / 4; ++g) {
        // issue next quad's gathers BEFORE this quad's stores
        fvec4 B0, B1, B2, B3;
        if (g + 1 < CCH / 4) {
            B0 = f0[g + 1];
            B1 = f1[g + 1];
            B2 = f2[g + 1];
            B3 = f3[g + 1];
        }

        fvec4 a0 = o0 ? A0 : zero;       // v_cndmask x4
        fvec4 a1 = o1 ? A1 : zero;
        fvec4 a2 = o2 ? A2 : zero;
        fvec4 a3 = o3 ? A3 : zero;

        // transpose: plane c=4g+k gets {cell0[k], cell1[k], cell2[k], cell3[k]}
        fvec4 v0 = {a0.x, a1.x, a2.x, a3.x};
        fvec4 v1 = {a0.y, a1.y, a2.y, a3.y};
        fvec4 v2 = {a0.z, a1.z, a2.z, a3.z};
        fvec4 v3 = {a0.w, a1.w, a2.w, a3.w};
        __builtin_nontemporal_store(v0, (fvec4*)(outp + (size_t)(4 * g + 0) * NXY));
        __builtin_nontemporal_store(v1, (fvec4*)(outp + (size_t)(4 * g + 1) * NXY));
        __builtin_nontemporal_store(v2, (fvec4*)(outp + (size_t)(4 * g + 2) * NXY));
        __builtin_nontemporal_store(v3, (fvec4*)(outp + (size_t)(4 * g + 3) * NXY));

        A0 = B0; A1 = B1; A2 = B2; A3 = B3;
    }
}

extern "C" void kernel_launch(void* const* d_in, const int* in_sizes, int n_in,
                              void* d_out, int out_size, void* d_ws, size_t ws_size,
                              hipStream_t stream) {
    const float* feat  = (const float*)d_in[0];   // [N, 64] fp32
    const int* coords  = (const int*)d_in[1];     // [N, 4] int32 (b, _, y, x)
    float* out         = (float*)d_out;           // [B, 64, NY, NX] fp32

    const int n_pillars = in_sizes[1] / 4;
    const int batch     = out_size / (CCH * NXY);
    const int total_pos = batch * NXY;            // 1.28M cells

    int* map = (int*)d_ws;                        // batch*NXY*4 = 5.12 MB

    // K1: reset map every call (d_ws not re-poisoned between replays)
    pps_init_map<<<1024, 256, 0, stream>>>((ivec4*)map, total_pos / 4);

    // K2: scatter pillar indices into the map
    pps_build_map<<<(n_pillars + 255) / 256, 256, 0, stream>>>(coords, map, n_pillars);

    // K3: gather pass — 256-thread blocks (1250 blocks, balanced ~4.9/CU)
    {
        int threads = total_pos / 4;              // 320000
        pps_gather_out<<<(threads + 255) / 256, 256, 0, stream>>>(feat, map, out, total_pos);
    }
}